// Round 7
// baseline (231.950 us; speedup 1.0000x reference)
//
#include <hip/hip_runtime.h>
#include <hip/hip_bf16.h>

// Shapes: b=2,t=8,l=1024,c=256,h=8,d=32 -> NTOK=16384, BTH=128
// Inputs/outputs: float32. ws intermediates: _Float16.
// ws layout (f16): qn | kn | vt | xa, each 4194304 elems (8MB) -> 32MB
//   qn/kn/xa: [bth][l][32]; vt TRANSPOSED: [bth][32][l]
//   W-f16 scratch (Wq|Wk|Wv) aliases the xa region (consumed by proj_mfma
//   before attn overwrites xa; stream order guarantees safety).
// qn is pre-scaled by log2(e)/sqrt(32); attn evaluates exp2 via a cubic
// polynomial in packed f16 (|s|<=0.26 -> Taylor rel err ~4e-5).
// Attention uses the K=16 layout identity: mfma_f32_16x16x16_f16's A-frag
// (A[m=l16][k=quad*4+i]) equals the 16x16 C/D layout (D[quad*4+r][l16]), so
// the exp'd S^T registers feed P*V directly — no LDS round-trip.

#define NTOK  16384
#define CDIM  256
#define LSEQ  1024
#define HEADS 8
#define DHEAD 32

typedef _Float16 f16;
typedef __attribute__((ext_vector_type(2))) _Float16 f16x2;
typedef __attribute__((ext_vector_type(4))) _Float16 f16x4;
typedef __attribute__((ext_vector_type(8))) _Float16 f16x8;
typedef __attribute__((ext_vector_type(4))) float f32x4;

#define QSCALE (0.17677669529663687f * 1.4426950408889634f)  // 1/sqrt(32)*log2e

__device__ __forceinline__ f16x2 pkcvt(float a, float b) {
  auto r = __builtin_amdgcn_cvt_pkrtz(a, b);  // v_cvt_pkrtz_f16_f32
  union { decltype(r) in; f16x2 out; } u;
  u.in = r;
  return u.out;
}

__device__ __forceinline__ f16x8 cvt8(const float* p) {
  float4 a = *(const float4*)p;
  float4 b = *(const float4*)(p + 4);
  union { f16x8 v; f16x2 h[4]; } u;
  u.h[0] = pkcvt(a.x, a.y);
  u.h[1] = pkcvt(a.z, a.w);
  u.h[2] = pkcvt(b.x, b.y);
  u.h[3] = pkcvt(b.z, b.w);
  return u.v;
}

// async global->LDS, 16B per lane; LDS dest = uniform base + lane*16
__device__ __forceinline__ void load_lds16(const void* g, void* l) {
  __builtin_amdgcn_global_load_lds(
      (const __attribute__((address_space(1))) void*)g,
      (__attribute__((address_space(3))) void*)l, 16, 0, 0);
}

// exp2 on packed f16, |x| <= 0.26: cubic Taylor in pk-f16 FMAs
__device__ __forceinline__ f16x2 exp2pk(f16x2 h) {
  const f16x2 C3 = {(f16)0.05550411f, (f16)0.05550411f};
  const f16x2 C2 = {(f16)0.24022651f, (f16)0.24022651f};
  const f16x2 C1 = {(f16)0.69314718f, (f16)0.69314718f};
  const f16x2 ONE = {(f16)1.0f, (f16)1.0f};
  f16x2 t = C2 + h * C3;
  t = C1 + h * t;
  return ONE + h * t;
}

// ---------------------------------------------------------------------------
// Kernel 0: convert Wq|Wk|Wv (each 256x256 f32) to f16, packed consecutively.
// ---------------------------------------------------------------------------
__global__ __launch_bounds__(256)
void cvt_w_kernel(const float* __restrict__ Wq, const float* __restrict__ Wk,
                  const float* __restrict__ Wv, f16* __restrict__ dst) {
  const int m = blockIdx.x >> 6;
  const float* src = (m == 0) ? Wq : (m == 1) ? Wk : Wv;
  const int base = (blockIdx.x & 63) * 1024 + threadIdx.x * 4;
  float4 a = *(const float4*)(src + base);
  union { f16x4 v; f16x2 h[2]; } u;
  u.h[0] = pkcvt(a.x, a.y);
  u.h[1] = pkcvt(a.z, a.w);
  *(f16x4*)(dst + m * 65536 + base) = u.v;
}

// ---------------------------------------------------------------------------
// Kernel 1: fused Q/K/V projection + bias + per-head L2-norm via MFMA.
// (unchanged from round 6)
// ---------------------------------------------------------------------------
__global__ __launch_bounds__(256, 4)
void proj_mfma_kernel(const float* __restrict__ xq, const float* __restrict__ xk,
                      const float* __restrict__ xv, const f16* __restrict__ w16,
                      const float* __restrict__ bq, const float* __restrict__ bk,
                      const float* __restrict__ bv,
                      f16* __restrict__ qn, f16* __restrict__ kn,
                      f16* __restrict__ vt) {
  __shared__ __align__(16) float xs[32][260];  // 33.3KB, +4 f32 row pad
  const int which = blockIdx.y;
  const float* x    = (which == 0) ? xq : (which == 1) ? xk : xv;
  const float* bias = (which == 0) ? bq : (which == 1) ? bk : bv;
  const f16* W      = w16 + which * 65536;
  f16* out          = (which == 0) ? qn : (which == 1) ? kn : vt;
  const float scale = (which == 0) ? QSCALE : 1.0f;
  const bool transposed = (which == 2);

  const int tid = threadIdx.x;
  const int wave = tid >> 6, lane = tid & 63;
  const int quad = lane >> 4, l16 = lane & 15;
  const int tokbase = blockIdx.x * 32;
  const int wbase = wave * 64;

#pragma unroll
  for (int i = 0; i < 8; ++i) {
    const int r = wave * 8 + i;
    load_lds16(x + (((size_t)(tokbase + r)) << 8) + lane * 4, &xs[r][0]);
  }
  __syncthreads();

  f32x4 acc[4][2];
#pragma unroll
  for (int mt = 0; mt < 4; ++mt)
#pragma unroll
    for (int nt = 0; nt < 2; ++nt) acc[mt][nt] = (f32x4){0.f, 0.f, 0.f, 0.f};

#pragma unroll
  for (int kk = 0; kk < 8; ++kk) {
    f16x8 af[4], bf[2];
#pragma unroll
    for (int mt = 0; mt < 4; ++mt)
      af[mt] = *(const f16x8*)(W + (size_t)(wbase + mt * 16 + l16) * CDIM +
                               kk * 32 + quad * 8);
#pragma unroll
    for (int nt = 0; nt < 2; ++nt)
      bf[nt] = cvt8(&xs[nt * 16 + l16][kk * 32 + quad * 8]);
#pragma unroll
    for (int mt = 0; mt < 4; ++mt)
#pragma unroll
      for (int nt = 0; nt < 2; ++nt)
        acc[mt][nt] = __builtin_amdgcn_mfma_f32_16x16x32_f16(af[mt], bf[nt],
                                                             acc[mt][nt], 0, 0, 0);
  }

  const int bt = tokbase >> 10, l0 = tokbase & 1023;
#pragma unroll
  for (int hh = 0; hh < 2; ++hh) {
    const int h = wave * 2 + hh;
    const size_t hb = (size_t)(bt * HEADS + h) * (LSEQ * DHEAD);
    float4 b0 = *(const float4*)(bias + wbase + hh * 32 + quad * 4);
    float4 b1 = *(const float4*)(bias + wbase + hh * 32 + 16 + quad * 4);
#pragma unroll
    for (int nt = 0; nt < 2; ++nt) {
      f32x4 a0 = acc[hh * 2 + 0][nt];
      f32x4 a1 = acc[hh * 2 + 1][nt];
      float v0[4], v1[4];
      v0[0] = a0[0] + b0.x; v0[1] = a0[1] + b0.y;
      v0[2] = a0[2] + b0.z; v0[3] = a0[3] + b0.w;
      v1[0] = a1[0] + b1.x; v1[1] = a1[1] + b1.y;
      v1[2] = a1[2] + b1.z; v1[3] = a1[3] + b1.w;
      float ss = 0.f;
#pragma unroll
      for (int r = 0; r < 4; ++r) ss += v0[r] * v0[r] + v1[r] * v1[r];
      ss += __shfl_xor(ss, 16);
      ss += __shfl_xor(ss, 32);
      const float inv = scale / fmaxf(sqrtf(ss), 1e-12f);
      const int tok_l = l0 + nt * 16 + l16;
      if (!transposed) {
        f16x4 o0, o1;
#pragma unroll
        for (int r = 0; r < 4; ++r) {
          o0[r] = (f16)(v0[r] * inv);
          o1[r] = (f16)(v1[r] * inv);
        }
        *(f16x4*)(out + hb + (size_t)tok_l * DHEAD + quad * 4) = o0;
        *(f16x4*)(out + hb + (size_t)tok_l * DHEAD + 16 + quad * 4) = o1;
      } else {
#pragma unroll
        for (int r = 0; r < 4; ++r) {
          out[hb + (size_t)(quad * 4 + r) * LSEQ + tok_l] = (f16)(v0[r] * inv);
          out[hb + (size_t)(16 + quad * 4 + r) * LSEQ + tok_l] = (f16)(v1[r] * inv);
        }
      }
    }
  }
}

// ---------------------------------------------------------------------------
// Kernel 2: MFMA attention, register-only P path.
// Per 16-key tile: S^T = K*Q^T (one 16x16x32 MFMA) -> packed-f16 exp2 in
// registers -> P (already in 16x16x16 A-frag layout) feeds 2 PV MFMAs
// (d-halves, B = contiguous f16x4 from vt) + 1 ones-MFMA (lsum rows land in
// the storing lane). No LDS, no cross-lane ops, 16 independent chains per
// 128-key chunk.
// ---------------------------------------------------------------------------
__global__ __launch_bounds__(256, 4)
void attn_mfma_kernel(const f16* __restrict__ qn,
                      const f16* __restrict__ kn,
                      const f16* __restrict__ vt,
                      f16* __restrict__ xo) {
  const int tid  = threadIdx.x;
  const int wave = tid >> 6, lane = tid & 63;
  const int quad = lane >> 4, l16 = lane & 15;
  const int xcd = blockIdx.x & 7;
  const int idx = blockIdx.x >> 3;
  const int bth = ((idx & 15) << 3) | xcd;
  const int qpart = idx >> 4;  // 0..7
  const int qbase = qpart * 128 + wave * 32;
  const size_t hb = (size_t)bth * (LSEQ * DHEAD);

  f16x8 qf[2];
#pragma unroll
  for (int qt = 0; qt < 2; ++qt)
    qf[qt] = *(const f16x8*)(qn + hb +
                             (size_t)(qbase + qt * 16 + l16) * DHEAD + quad * 8);

  const f16x4 ones4 = {(f16)1.f, (f16)1.f, (f16)1.f, (f16)1.f};

  f32x4 oacc[2][2], ol[2];
#pragma unroll
  for (int qt = 0; qt < 2; ++qt) {
    ol[qt] = (f32x4){0.f, 0.f, 0.f, 0.f};
#pragma unroll
    for (int h = 0; h < 2; ++h) oacc[qt][h] = (f32x4){0.f, 0.f, 0.f, 0.f};
  }

  for (int kb = 0; kb < LSEQ; kb += 128) {
    // K A-frags (K=32 S-MFMA): A[m=key][k=d] = K[kb+t*16+l16][quad*8+j]
    f16x8 kf[8];
#pragma unroll
    for (int t = 0; t < 8; ++t)
      kf[t] = *(const f16x8*)(kn + hb +
                              (size_t)(kb + t * 16 + l16) * DHEAD + quad * 8);
    // V B-frags (K=16 PV MFMA): B[k=key][n=d] = V[kb+t*16+quad*4+i][h*16+l16]
    //  = vt[h*16+l16][kb+t*16+quad*4+i] -> contiguous f16x4
    f16x4 vf[8][2];
#pragma unroll
    for (int t = 0; t < 8; ++t)
#pragma unroll
      for (int h = 0; h < 2; ++h)
        vf[t][h] = *(const f16x4*)(vt + hb + (size_t)(h * 16 + l16) * LSEQ +
                                   kb + t * 16 + quad * 4);

#pragma unroll
    for (int qt = 0; qt < 2; ++qt) {
#pragma unroll
      for (int t = 0; t < 8; ++t) {
        const f32x4 z = {0.f, 0.f, 0.f, 0.f};
        // S^T tile: D[row=key=quad*4+r][col=q=l16], K=32 over d
        f32x4 s = __builtin_amdgcn_mfma_f32_16x16x32_f16(kf[t], qf[qt], z,
                                                         0, 0, 0);
        union { f16x4 v; f16x2 h[2]; } p;
        p.h[0] = exp2pk(pkcvt(s[0], s[1]));
        p.h[1] = exp2pk(pkcvt(s[2], s[3]));
        // D-layout == 16x16x16 A-layout: p is A[m=q=l16][k=key=quad*4+i]
        oacc[qt][0] = __builtin_amdgcn_mfma_f32_16x16x16f16(
            p.v, vf[t][0], oacc[qt][0], 0, 0, 0);
        oacc[qt][1] = __builtin_amdgcn_mfma_f32_16x16x16f16(
            p.v, vf[t][1], oacc[qt][1], 0, 0, 0);
        ol[qt] = __builtin_amdgcn_mfma_f32_16x16x16f16(p.v, ones4, ol[qt],
                                                       0, 0, 0);
      }
    }
  }

  // epilogue: lane (quad,l16) holds rows quad*4+r; ol has lsum[row] in-lane
#pragma unroll
  for (int qt = 0; qt < 2; ++qt) {
#pragma unroll
    for (int r = 0; r < 4; ++r) {
      float inv = 1.f / ol[qt][r];
      int row = qbase + qt * 16 + quad * 4 + r;
#pragma unroll
      for (int h = 0; h < 2; ++h)
        xo[hb + (size_t)row * DHEAD + h * 16 + l16] =
            (f16)(oacc[qt][h][r] * inv);
    }
  }
}

// ---------------------------------------------------------------------------
// Kernel 3: out = xatt @ Wm^T + bm + residual, f32 out, via MFMA.
// (unchanged from round 6)
// ---------------------------------------------------------------------------
__global__ __launch_bounds__(256, 4)
void out_proj_mfma_kernel(const f16* __restrict__ xatt,
                          const float* __restrict__ Wm,
                          const float* __restrict__ bm,
                          const float* __restrict__ resid,
                          float* __restrict__ out) {
  const int tid = threadIdx.x;
  const int wave = tid >> 6, lane = tid & 63;
  const int quad = lane >> 4, l16 = lane & 15;
  const int tokbase = blockIdx.x * 32;
  const int wbase = wave * 64;
  const int bt = tokbase >> 10, l0 = tokbase & 1023;

  f32x4 acc[2][4];  // [m=tok tile][n=och tile]
#pragma unroll
  for (int mt = 0; mt < 2; ++mt)
#pragma unroll
    for (int nt = 0; nt < 4; ++nt) acc[mt][nt] = (f32x4){0.f, 0.f, 0.f, 0.f};

#pragma unroll
  for (int kk = 0; kk < 8; ++kk) {
    const size_t hb = (size_t)(bt * HEADS + kk) * (LSEQ * DHEAD);
    f16x8 af[2], bf[4];
#pragma unroll
    for (int mt = 0; mt < 2; ++mt)
      af[mt] = *(const f16x8*)(xatt + hb +
                               (size_t)(l0 + mt * 16 + l16) * DHEAD + quad * 8);
#pragma unroll
    for (int nt = 0; nt < 4; ++nt)
      bf[nt] = cvt8(Wm + (size_t)(wbase + nt * 16 + l16) * CDIM + kk * 32 +
                    quad * 8);
#pragma unroll
    for (int mt = 0; mt < 2; ++mt)
#pragma unroll
      for (int nt = 0; nt < 4; ++nt)
        acc[mt][nt] = __builtin_amdgcn_mfma_f32_16x16x32_f16(af[mt], bf[nt],
                                                             acc[mt][nt], 0, 0, 0);
  }

#pragma unroll
  for (int nt = 0; nt < 4; ++nt) {
    const int och = wbase + nt * 16 + l16;
    const float bv = bm[och];
#pragma unroll
    for (int mt = 0; mt < 2; ++mt) {
#pragma unroll
      for (int r = 0; r < 4; ++r) {
        const int tok = tokbase + mt * 16 + quad * 4 + r;
        const size_t off = (size_t)tok * CDIM + och;
        out[off] = acc[mt][nt][r] + bv + resid[off];
      }
    }
  }
}

extern "C" void kernel_launch(void* const* d_in, const int* in_sizes, int n_in,
                              void* d_out, int out_size, void* d_ws,
                              size_t ws_size, hipStream_t stream) {
  const float* q  = (const float*)d_in[0];
  const float* k  = (const float*)d_in[1];
  const float* v  = (const float*)d_in[2];
  const float* Wq = (const float*)d_in[3];
  const float* bq = (const float*)d_in[4];
  const float* Wk = (const float*)d_in[5];
  const float* bk = (const float*)d_in[6];
  const float* Wv = (const float*)d_in[7];
  const float* bv = (const float*)d_in[8];
  const float* Wm = (const float*)d_in[9];
  const float* bm = (const float*)d_in[10];
  float* outp = (float*)d_out;

  f16* ws = (f16*)d_ws;
  const size_t TENS = (size_t)NTOK * CDIM;  // 4194304
  f16* qn  = ws;
  f16* kn  = ws + TENS;
  f16* vt  = ws + 2 * TENS;
  f16* xa  = ws + 3 * TENS;
  f16* w16 = xa;  // alias: consumed by proj_mfma before attn writes xa

  dim3 blk(256);
  cvt_w_kernel<<<dim3(192), blk, 0, stream>>>(Wq, Wk, Wv, w16);
  proj_mfma_kernel<<<dim3(512, 3), blk, 0, stream>>>(q, k, v, w16, bq, bk, bv,
                                                     qn, kn, vt);
  attn_mfma_kernel<<<dim3(1024), blk, 0, stream>>>(qn, kn, vt, xa);
  out_proj_mfma_kernel<<<dim3(512), blk, 0, stream>>>(xa, Wm, bm, q, outp);
}

// Round 8
// 216.710 us; speedup vs baseline: 1.0703x; 1.0703x over previous
//
#include <hip/hip_runtime.h>
#include <hip/hip_bf16.h>

// Shapes: b=2,t=8,l=1024,c=256,h=8,d=32 -> NTOK=16384, BTH=128
// Inputs/outputs: float32. ws intermediates: _Float16.
// ws layout (f16): qn | kn | vt | xa, each 4194304 elems (8MB) -> 32MB
//   qn/kn/xa: [bth][l][32]; vt TRANSPOSED: [bth][32][l]
//   W-f16 scratch (Wq|Wk|Wv) aliases the xa region (consumed by proj_mfma
//   before attn overwrites xa; stream order guarantees safety).
// qn is pre-scaled by log2(e)/sqrt(32); attn evaluates exp2 via a cubic
// polynomial in packed f16 (|s|<=0.26 -> Taylor rel err ~4e-5).
// Attention: K=32 MFMAs only (K=16 runs at the same cycle cost — measured
// round 7), P routed through per-subtile LDS slots (8/wave) so subtile
// chains pipeline instead of serializing on one buffer's WAR hazard.

#define NTOK  16384
#define CDIM  256
#define LSEQ  1024
#define HEADS 8
#define DHEAD 32

typedef _Float16 f16;
typedef __attribute__((ext_vector_type(2))) _Float16 f16x2;
typedef __attribute__((ext_vector_type(4))) _Float16 f16x4;
typedef __attribute__((ext_vector_type(8))) _Float16 f16x8;
typedef __attribute__((ext_vector_type(4))) float f32x4;

#define QSCALE (0.17677669529663687f * 1.4426950408889634f)  // 1/sqrt(32)*log2e

__device__ __forceinline__ f16x2 pkcvt(float a, float b) {
  auto r = __builtin_amdgcn_cvt_pkrtz(a, b);  // v_cvt_pkrtz_f16_f32
  union { decltype(r) in; f16x2 out; } u;
  u.in = r;
  return u.out;
}

__device__ __forceinline__ f16x8 cvt8(const float* p) {
  float4 a = *(const float4*)p;
  float4 b = *(const float4*)(p + 4);
  union { f16x8 v; f16x2 h[4]; } u;
  u.h[0] = pkcvt(a.x, a.y);
  u.h[1] = pkcvt(a.z, a.w);
  u.h[2] = pkcvt(b.x, b.y);
  u.h[3] = pkcvt(b.z, b.w);
  return u.v;
}

// async global->LDS, 16B per lane; LDS dest = uniform base + lane*16
__device__ __forceinline__ void load_lds16(const void* g, void* l) {
  __builtin_amdgcn_global_load_lds(
      (const __attribute__((address_space(1))) void*)g,
      (__attribute__((address_space(3))) void*)l, 16, 0, 0);
}

// exp2 on packed f16, |x| <= 0.26: cubic Taylor in pk-f16 FMAs
__device__ __forceinline__ f16x2 exp2pk(f16x2 h) {
  const f16x2 C3 = {(f16)0.05550411f, (f16)0.05550411f};
  const f16x2 C2 = {(f16)0.24022651f, (f16)0.24022651f};
  const f16x2 C1 = {(f16)0.69314718f, (f16)0.69314718f};
  const f16x2 ONE = {(f16)1.0f, (f16)1.0f};
  f16x2 t = C2 + h * C3;
  t = C1 + h * t;
  return ONE + h * t;
}

// ---------------------------------------------------------------------------
// Kernel 0: convert Wq|Wk|Wv (each 256x256 f32) to f16, packed consecutively.
// ---------------------------------------------------------------------------
__global__ __launch_bounds__(256)
void cvt_w_kernel(const float* __restrict__ Wq, const float* __restrict__ Wk,
                  const float* __restrict__ Wv, f16* __restrict__ dst) {
  const int m = blockIdx.x >> 6;
  const float* src = (m == 0) ? Wq : (m == 1) ? Wk : Wv;
  const int base = (blockIdx.x & 63) * 1024 + threadIdx.x * 4;
  float4 a = *(const float4*)(src + base);
  union { f16x4 v; f16x2 h[2]; } u;
  u.h[0] = pkcvt(a.x, a.y);
  u.h[1] = pkcvt(a.z, a.w);
  *(f16x4*)(dst + m * 65536 + base) = u.v;
}

// ---------------------------------------------------------------------------
// Kernel 1: fused Q/K/V projection + bias + per-head L2-norm via MFMA.
// (unchanged from round 6/7)
// ---------------------------------------------------------------------------
__global__ __launch_bounds__(256, 4)
void proj_mfma_kernel(const float* __restrict__ xq, const float* __restrict__ xk,
                      const float* __restrict__ xv, const f16* __restrict__ w16,
                      const float* __restrict__ bq, const float* __restrict__ bk,
                      const float* __restrict__ bv,
                      f16* __restrict__ qn, f16* __restrict__ kn,
                      f16* __restrict__ vt) {
  __shared__ __align__(16) float xs[32][260];  // 33.3KB, +4 f32 row pad
  const int which = blockIdx.y;
  const float* x    = (which == 0) ? xq : (which == 1) ? xk : xv;
  const float* bias = (which == 0) ? bq : (which == 1) ? bk : bv;
  const f16* W      = w16 + which * 65536;
  f16* out          = (which == 0) ? qn : (which == 1) ? kn : vt;
  const float scale = (which == 0) ? QSCALE : 1.0f;
  const bool transposed = (which == 2);

  const int tid = threadIdx.x;
  const int wave = tid >> 6, lane = tid & 63;
  const int quad = lane >> 4, l16 = lane & 15;
  const int tokbase = blockIdx.x * 32;
  const int wbase = wave * 64;

#pragma unroll
  for (int i = 0; i < 8; ++i) {
    const int r = wave * 8 + i;
    load_lds16(x + (((size_t)(tokbase + r)) << 8) + lane * 4, &xs[r][0]);
  }
  __syncthreads();

  f32x4 acc[4][2];
#pragma unroll
  for (int mt = 0; mt < 4; ++mt)
#pragma unroll
    for (int nt = 0; nt < 2; ++nt) acc[mt][nt] = (f32x4){0.f, 0.f, 0.f, 0.f};

#pragma unroll
  for (int kk = 0; kk < 8; ++kk) {
    f16x8 af[4], bf[2];
#pragma unroll
    for (int mt = 0; mt < 4; ++mt)
      af[mt] = *(const f16x8*)(W + (size_t)(wbase + mt * 16 + l16) * CDIM +
                               kk * 32 + quad * 8);
#pragma unroll
    for (int nt = 0; nt < 2; ++nt)
      bf[nt] = cvt8(&xs[nt * 16 + l16][kk * 32 + quad * 8]);
#pragma unroll
    for (int mt = 0; mt < 4; ++mt)
#pragma unroll
      for (int nt = 0; nt < 2; ++nt)
        acc[mt][nt] = __builtin_amdgcn_mfma_f32_16x16x32_f16(af[mt], bf[nt],
                                                             acc[mt][nt], 0, 0, 0);
  }

  const int bt = tokbase >> 10, l0 = tokbase & 1023;
#pragma unroll
  for (int hh = 0; hh < 2; ++hh) {
    const int h = wave * 2 + hh;
    const size_t hb = (size_t)(bt * HEADS + h) * (LSEQ * DHEAD);
    float4 b0 = *(const float4*)(bias + wbase + hh * 32 + quad * 4);
    float4 b1 = *(const float4*)(bias + wbase + hh * 32 + 16 + quad * 4);
#pragma unroll
    for (int nt = 0; nt < 2; ++nt) {
      f32x4 a0 = acc[hh * 2 + 0][nt];
      f32x4 a1 = acc[hh * 2 + 1][nt];
      float v0[4], v1[4];
      v0[0] = a0[0] + b0.x; v0[1] = a0[1] + b0.y;
      v0[2] = a0[2] + b0.z; v0[3] = a0[3] + b0.w;
      v1[0] = a1[0] + b1.x; v1[1] = a1[1] + b1.y;
      v1[2] = a1[2] + b1.z; v1[3] = a1[3] + b1.w;
      float ss = 0.f;
#pragma unroll
      for (int r = 0; r < 4; ++r) ss += v0[r] * v0[r] + v1[r] * v1[r];
      ss += __shfl_xor(ss, 16);
      ss += __shfl_xor(ss, 32);
      const float inv = scale / fmaxf(sqrtf(ss), 1e-12f);
      const int tok_l = l0 + nt * 16 + l16;
      if (!transposed) {
        f16x4 o0, o1;
#pragma unroll
        for (int r = 0; r < 4; ++r) {
          o0[r] = (f16)(v0[r] * inv);
          o1[r] = (f16)(v1[r] * inv);
        }
        *(f16x4*)(out + hb + (size_t)tok_l * DHEAD + quad * 4) = o0;
        *(f16x4*)(out + hb + (size_t)tok_l * DHEAD + 16 + quad * 4) = o1;
      } else {
#pragma unroll
        for (int r = 0; r < 4; ++r) {
          out[hb + (size_t)(quad * 4 + r) * LSEQ + tok_l] = (f16)(v0[r] * inv);
          out[hb + (size_t)(16 + quad * 4 + r) * LSEQ + tok_l] = (f16)(v1[r] * inv);
        }
      }
    }
  }
}

// ---------------------------------------------------------------------------
// Kernel 2: MFMA attention, K=32 MFMAs + per-subtile LDS slots.
// Block = 128 q rows of one head; wave = 32 rows (2 q-tiles). Per 128-key
// chunk: 4 key-subtiles (32 keys) x 2 q-tiles = 8 independent chains, each
// with its OWN LDS slot (no WAR aliasing -> compiler can pipeline chains).
// Chain: 2x S^T MFMA (K=32) -> pk-f16 exp2 -> 2x ds_write_b64 ->
// ds_read_b128 -> 2 PV MFMA + 1 ones-MFMA (lsum), all 16x16x32.
// ---------------------------------------------------------------------------
__global__ __launch_bounds__(256, 4)
void attn_mfma_kernel(const f16* __restrict__ qn,
                      const f16* __restrict__ kn,
                      const f16* __restrict__ vt,
                      f16* __restrict__ xo) {
  __shared__ f16 pbuf[4][8][16 * 40];  // 40KB: wave x slot x (16x40)
  const int tid  = threadIdx.x;
  const int wave = tid >> 6, lane = tid & 63;
  const int quad = lane >> 4, l16 = lane & 15;
  const int xcd = blockIdx.x & 7;
  const int idx = blockIdx.x >> 3;
  const int bth = ((idx & 15) << 3) | xcd;
  const int qpart = idx >> 4;  // 0..7
  const int qbase = qpart * 128 + wave * 32;
  const size_t hb = (size_t)bth * (LSEQ * DHEAD);
  f16* pw = &pbuf[wave][0][0];

  f16x8 qf[2];
#pragma unroll
  for (int qt = 0; qt < 2; ++qt)
    qf[qt] = *(const f16x8*)(qn + hb +
                             (size_t)(qbase + qt * 16 + l16) * DHEAD + quad * 8);

  const f16x8 ones = {(f16)1.f, (f16)1.f, (f16)1.f, (f16)1.f,
                      (f16)1.f, (f16)1.f, (f16)1.f, (f16)1.f};

  f32x4 oacc[2][2], ol[2];
#pragma unroll
  for (int qt = 0; qt < 2; ++qt) {
    ol[qt] = (f32x4){0.f, 0.f, 0.f, 0.f};
#pragma unroll
    for (int h = 0; h < 2; ++h) oacc[qt][h] = (f32x4){0.f, 0.f, 0.f, 0.f};
  }

  for (int kb = 0; kb < LSEQ; kb += 128) {
#pragma unroll
    for (int c = 0; c < 4; ++c) {
      // K A-frags for this 32-key subtile (2 x 16 rows)
      f16x8 k0 = *(const f16x8*)(kn + hb +
                                 (size_t)(kb + c * 32 + l16) * DHEAD + quad * 8);
      f16x8 k1 = *(const f16x8*)(kn + hb +
                                 (size_t)(kb + c * 32 + 16 + l16) * DHEAD +
                                 quad * 8);
      // V B-frags: B[k=key][n=d], contiguous from vt [bth][32][l]
      f16x8 v0 = *(const f16x8*)(vt + hb + (size_t)l16 * LSEQ + kb + c * 32 +
                                 quad * 8);
      f16x8 v1 = *(const f16x8*)(vt + hb + (size_t)(16 + l16) * LSEQ + kb +
                                 c * 32 + quad * 8);
#pragma unroll
      for (int qt = 0; qt < 2; ++qt) {
        f16* ps = pw + (c * 2 + qt) * (16 * 40);  // private slot
        const f32x4 z = {0.f, 0.f, 0.f, 0.f};
        // S^T tiles: D[row=key=quad*4+r][col=q=l16]
        f32x4 s0 = __builtin_amdgcn_mfma_f32_16x16x32_f16(k0, qf[qt], z, 0, 0, 0);
        f32x4 s1 = __builtin_amdgcn_mfma_f32_16x16x32_f16(k1, qf[qt], z, 0, 0, 0);
        union { f16x4 v; f16x2 h[2]; } p0, p1;
        p0.h[0] = exp2pk(pkcvt(s0[0], s0[1]));
        p0.h[1] = exp2pk(pkcvt(s0[2], s0[3]));
        p1.h[0] = exp2pk(pkcvt(s1[0], s1[1]));
        p1.h[1] = exp2pk(pkcvt(s1[2], s1[3]));
        // P[q=l16][key]: keys quad*4+r (tile0), 16+quad*4+r (tile1)
        *(f16x4*)(ps + l16 * 40 + quad * 4)      = p0.v;
        *(f16x4*)(ps + l16 * 40 + 16 + quad * 4) = p1.v;
        // A-frag: P[m=l16][k=quad*8+j]
        f16x8 pf = *(const f16x8*)(ps + l16 * 40 + quad * 8);
        oacc[qt][0] = __builtin_amdgcn_mfma_f32_16x16x32_f16(pf, v0,
                                                             oacc[qt][0], 0, 0, 0);
        oacc[qt][1] = __builtin_amdgcn_mfma_f32_16x16x32_f16(pf, v1,
                                                             oacc[qt][1], 0, 0, 0);
        ol[qt] = __builtin_amdgcn_mfma_f32_16x16x32_f16(pf, ones, ol[qt],
                                                        0, 0, 0);
      }
    }
  }

  // epilogue: lane (quad,l16) holds rows quad*4+r; ol has lsum[row] in-lane
#pragma unroll
  for (int qt = 0; qt < 2; ++qt) {
#pragma unroll
    for (int r = 0; r < 4; ++r) {
      float inv = 1.f / ol[qt][r];
      int row = qbase + qt * 16 + quad * 4 + r;
#pragma unroll
      for (int h = 0; h < 2; ++h)
        xo[hb + (size_t)row * DHEAD + h * 16 + l16] =
            (f16)(oacc[qt][h][r] * inv);
    }
  }
}

// ---------------------------------------------------------------------------
// Kernel 3: out = xatt @ Wm^T + bm + residual, f32 out, via MFMA.
// Grid 1024 (16 tokens/block -> 4 blocks/CU). D[m=tok][n=och].
// ---------------------------------------------------------------------------
__global__ __launch_bounds__(256, 4)
void out_proj_mfma_kernel(const f16* __restrict__ xatt,
                          const float* __restrict__ Wm,
                          const float* __restrict__ bm,
                          const float* __restrict__ resid,
                          float* __restrict__ out) {
  const int tid = threadIdx.x;
  const int wave = tid >> 6, lane = tid & 63;
  const int quad = lane >> 4, l16 = lane & 15;
  const int tokbase = blockIdx.x * 16;
  const int wbase = wave * 64;
  const int bt = tokbase >> 10, l0 = tokbase & 1023;

  f32x4 acc[4];  // [n=och tile]
#pragma unroll
  for (int nt = 0; nt < 4; ++nt) acc[nt] = (f32x4){0.f, 0.f, 0.f, 0.f};

#pragma unroll
  for (int kk = 0; kk < 8; ++kk) {
    const size_t hb = (size_t)(bt * HEADS + kk) * (LSEQ * DHEAD);
    f16x8 af = *(const f16x8*)(xatt + hb + (size_t)(l0 + l16) * DHEAD +
                               quad * 8);
    f16x8 bf[4];
#pragma unroll
    for (int nt = 0; nt < 4; ++nt)
      bf[nt] = cvt8(Wm + (size_t)(wbase + nt * 16 + l16) * CDIM + kk * 32 +
                    quad * 8);
#pragma unroll
    for (int nt = 0; nt < 4; ++nt)
      acc[nt] = __builtin_amdgcn_mfma_f32_16x16x32_f16(af, bf[nt], acc[nt],
                                                       0, 0, 0);
  }

  // C layout: row=quad*4+r -> tok, col=l16 -> och. Coalesced scalar stores.
#pragma unroll
  for (int nt = 0; nt < 4; ++nt) {
    const int och = wbase + nt * 16 + l16;
    const float bv = bm[och];
#pragma unroll
    for (int r = 0; r < 4; ++r) {
      const int tok = tokbase + quad * 4 + r;
      const size_t off = (size_t)tok * CDIM + och;
      out[off] = acc[nt][r] + bv + resid[off];
    }
  }
}

extern "C" void kernel_launch(void* const* d_in, const int* in_sizes, int n_in,
                              void* d_out, int out_size, void* d_ws,
                              size_t ws_size, hipStream_t stream) {
  const float* q  = (const float*)d_in[0];
  const float* k  = (const float*)d_in[1];
  const float* v  = (const float*)d_in[2];
  const float* Wq = (const float*)d_in[3];
  const float* bq = (const float*)d_in[4];
  const float* Wk = (const float*)d_in[5];
  const float* bk = (const float*)d_in[6];
  const float* Wv = (const float*)d_in[7];
  const float* bv = (const float*)d_in[8];
  const float* Wm = (const float*)d_in[9];
  const float* bm = (const float*)d_in[10];
  float* outp = (float*)d_out;

  f16* ws = (f16*)d_ws;
  const size_t TENS = (size_t)NTOK * CDIM;  // 4194304
  f16* qn  = ws;
  f16* kn  = ws + TENS;
  f16* vt  = ws + 2 * TENS;
  f16* xa  = ws + 3 * TENS;
  f16* w16 = xa;  // alias: consumed by proj_mfma before attn writes xa

  dim3 blk(256);
  cvt_w_kernel<<<dim3(192), blk, 0, stream>>>(Wq, Wk, Wv, w16);
  proj_mfma_kernel<<<dim3(512, 3), blk, 0, stream>>>(q, k, v, w16, bq, bk, bv,
                                                     qn, kn, vt);
  attn_mfma_kernel<<<dim3(1024), blk, 0, stream>>>(qn, kn, vt, xa);
  out_proj_mfma_kernel<<<dim3(1024), blk, 0, stream>>>(xa, Wm, bm, q, outp);
}

// Round 9
// 204.565 us; speedup vs baseline: 1.1339x; 1.0594x over previous
//
#include <hip/hip_runtime.h>
#include <hip/hip_bf16.h>

// Shapes: b=2,t=8,l=1024,c=256,h=8,d=32 -> NTOK=16384, BTH=128
// Inputs/outputs: float32. ws intermediates: _Float16.
// ws layout (f16): qn | kn | vt | xa, each 4194304 elems (8MB) -> 32MB
//   qn/kn/xa: [bth][l][32]; vt TRANSPOSED+PERMUTED: [bth][32][l'] where
//   within each 32-key block, key' = ((key>>2)&3)*8 + ((key>>4)&1)*4 + (key&3)
//   (the MFMA C->A fragment permutation; P and V share it, so PV is exact).
//   W-f16 scratch (Wq|Wk|Wv) aliases the xa region (consumed by proj_mfma
//   before attn overwrites xa; stream order guarantees safety).
// qn is pre-scaled by log2(e)/sqrt(32); attn evaluates exp2 via a cubic
// polynomial in packed f16 (|s|<=0.26 -> Taylor rel err ~4e-5).
// Attention K-loop is phase-separated: all 8 S/exp/ds_write chains, then V
// loads, then all 8 ds_read/PV chains -> ONE lgkm drain per 128-key chunk
// instead of one per chain (r8 lesson: in-order DS completion serializes
// write->read pairs regardless of slot privacy).

#define NTOK  16384
#define CDIM  256
#define LSEQ  1024
#define HEADS 8
#define DHEAD 32

typedef _Float16 f16;
typedef __attribute__((ext_vector_type(2))) _Float16 f16x2;
typedef __attribute__((ext_vector_type(4))) _Float16 f16x4;
typedef __attribute__((ext_vector_type(8))) _Float16 f16x8;
typedef __attribute__((ext_vector_type(4))) float f32x4;

#define QSCALE (0.17677669529663687f * 1.4426950408889634f)  // 1/sqrt(32)*log2e

__device__ __forceinline__ f16x2 pkcvt(float a, float b) {
  auto r = __builtin_amdgcn_cvt_pkrtz(a, b);  // v_cvt_pkrtz_f16_f32
  union { decltype(r) in; f16x2 out; } u;
  u.in = r;
  return u.out;
}

__device__ __forceinline__ f16x8 cvt8(const float* p) {
  float4 a = *(const float4*)p;
  float4 b = *(const float4*)(p + 4);
  union { f16x8 v; f16x2 h[4]; } u;
  u.h[0] = pkcvt(a.x, a.y);
  u.h[1] = pkcvt(a.z, a.w);
  u.h[2] = pkcvt(b.x, b.y);
  u.h[3] = pkcvt(b.z, b.w);
  return u.v;
}

// async global->LDS, 16B per lane; LDS dest = uniform base + lane*16
__device__ __forceinline__ void load_lds16(const void* g, void* l) {
  __builtin_amdgcn_global_load_lds(
      (const __attribute__((address_space(1))) void*)g,
      (__attribute__((address_space(3))) void*)l, 16, 0, 0);
}

// exp2 on packed f16, |x| <= 0.26: cubic Taylor in pk-f16 FMAs
__device__ __forceinline__ f16x2 exp2pk(f16x2 h) {
  const f16x2 C3 = {(f16)0.05550411f, (f16)0.05550411f};
  const f16x2 C2 = {(f16)0.24022651f, (f16)0.24022651f};
  const f16x2 C1 = {(f16)0.69314718f, (f16)0.69314718f};
  const f16x2 ONE = {(f16)1.0f, (f16)1.0f};
  f16x2 t = C2 + h * C3;
  t = C1 + h * t;
  return ONE + h * t;
}

// ---------------------------------------------------------------------------
// Kernel 0: convert Wq|Wk|Wv (each 256x256 f32) to f16, packed consecutively.
// ---------------------------------------------------------------------------
__global__ __launch_bounds__(256)
void cvt_w_kernel(const float* __restrict__ Wq, const float* __restrict__ Wk,
                  const float* __restrict__ Wv, f16* __restrict__ dst) {
  const int m = blockIdx.x >> 6;
  const float* src = (m == 0) ? Wq : (m == 1) ? Wk : Wv;
  const int base = (blockIdx.x & 63) * 1024 + threadIdx.x * 4;
  float4 a = *(const float4*)(src + base);
  union { f16x4 v; f16x2 h[2]; } u;
  u.h[0] = pkcvt(a.x, a.y);
  u.h[1] = pkcvt(a.z, a.w);
  *(f16x4*)(dst + m * 65536 + base) = u.v;
}

// ---------------------------------------------------------------------------
// Kernel 1: fused Q/K/V projection + bias + per-head L2-norm via MFMA.
// V store applies the key' permutation (see header) so attn's V B-frag is a
// single contiguous b128 in the permuted key space.
// ---------------------------------------------------------------------------
__global__ __launch_bounds__(256, 4)
void proj_mfma_kernel(const float* __restrict__ xq, const float* __restrict__ xk,
                      const float* __restrict__ xv, const f16* __restrict__ w16,
                      const float* __restrict__ bq, const float* __restrict__ bk,
                      const float* __restrict__ bv,
                      f16* __restrict__ qn, f16* __restrict__ kn,
                      f16* __restrict__ vt) {
  __shared__ __align__(16) float xs[32][260];  // 33.3KB, +4 f32 row pad
  const int which = blockIdx.y;
  const float* x    = (which == 0) ? xq : (which == 1) ? xk : xv;
  const float* bias = (which == 0) ? bq : (which == 1) ? bk : bv;
  const f16* W      = w16 + which * 65536;
  f16* out          = (which == 0) ? qn : (which == 1) ? kn : vt;
  const float scale = (which == 0) ? QSCALE : 1.0f;
  const bool transposed = (which == 2);

  const int tid = threadIdx.x;
  const int wave = tid >> 6, lane = tid & 63;
  const int quad = lane >> 4, l16 = lane & 15;
  const int tokbase = blockIdx.x * 32;
  const int wbase = wave * 64;

#pragma unroll
  for (int i = 0; i < 8; ++i) {
    const int r = wave * 8 + i;
    load_lds16(x + (((size_t)(tokbase + r)) << 8) + lane * 4, &xs[r][0]);
  }
  __syncthreads();

  f32x4 acc[4][2];
#pragma unroll
  for (int mt = 0; mt < 4; ++mt)
#pragma unroll
    for (int nt = 0; nt < 2; ++nt) acc[mt][nt] = (f32x4){0.f, 0.f, 0.f, 0.f};

#pragma unroll
  for (int kk = 0; kk < 8; ++kk) {
    f16x8 af[4], bf[2];
#pragma unroll
    for (int mt = 0; mt < 4; ++mt)
      af[mt] = *(const f16x8*)(W + (size_t)(wbase + mt * 16 + l16) * CDIM +
                               kk * 32 + quad * 8);
#pragma unroll
    for (int nt = 0; nt < 2; ++nt)
      bf[nt] = cvt8(&xs[nt * 16 + l16][kk * 32 + quad * 8]);
#pragma unroll
    for (int mt = 0; mt < 4; ++mt)
#pragma unroll
      for (int nt = 0; nt < 2; ++nt)
        acc[mt][nt] = __builtin_amdgcn_mfma_f32_16x16x32_f16(af[mt], bf[nt],
                                                             acc[mt][nt], 0, 0, 0);
  }

  const int bt = tokbase >> 10, l0 = tokbase & 1023;
#pragma unroll
  for (int hh = 0; hh < 2; ++hh) {
    const int h = wave * 2 + hh;
    const size_t hb = (size_t)(bt * HEADS + h) * (LSEQ * DHEAD);
    float4 b0 = *(const float4*)(bias + wbase + hh * 32 + quad * 4);
    float4 b1 = *(const float4*)(bias + wbase + hh * 32 + 16 + quad * 4);
#pragma unroll
    for (int nt = 0; nt < 2; ++nt) {
      f32x4 a0 = acc[hh * 2 + 0][nt];
      f32x4 a1 = acc[hh * 2 + 1][nt];
      float v0[4], v1[4];
      v0[0] = a0[0] + b0.x; v0[1] = a0[1] + b0.y;
      v0[2] = a0[2] + b0.z; v0[3] = a0[3] + b0.w;
      v1[0] = a1[0] + b1.x; v1[1] = a1[1] + b1.y;
      v1[2] = a1[2] + b1.z; v1[3] = a1[3] + b1.w;
      float ss = 0.f;
#pragma unroll
      for (int r = 0; r < 4; ++r) ss += v0[r] * v0[r] + v1[r] * v1[r];
      ss += __shfl_xor(ss, 16);
      ss += __shfl_xor(ss, 32);
      const float inv = scale / fmaxf(sqrtf(ss), 1e-12f);
      const int tok_l = l0 + nt * 16 + l16;
      if (!transposed) {
        f16x4 o0, o1;
#pragma unroll
        for (int r = 0; r < 4; ++r) {
          o0[r] = (f16)(v0[r] * inv);
          o1[r] = (f16)(v1[r] * inv);
        }
        *(f16x4*)(out + hb + (size_t)tok_l * DHEAD + quad * 4) = o0;
        *(f16x4*)(out + hb + (size_t)tok_l * DHEAD + 16 + quad * 4) = o1;
      } else {
        // permuted key position within the 32-block (matches attn's P/V frag)
        const int pk = (tok_l & ~31) | (((tok_l >> 2) & 3) << 3) |
                       (((tok_l >> 4) & 1) << 2) | (tok_l & 3);
#pragma unroll
        for (int r = 0; r < 4; ++r) {
          out[hb + (size_t)(quad * 4 + r) * LSEQ + pk] = (f16)(v0[r] * inv);
          out[hb + (size_t)(16 + quad * 4 + r) * LSEQ + pk] = (f16)(v1[r] * inv);
        }
      }
    }
  }
}

// ---------------------------------------------------------------------------
// Kernel 2: MFMA attention, phase-batched P transpose.
// Block = 128 q rows of one head; wave = 32 rows (2 q-tiles).
// Per 128-key chunk: Phase A = 8 chains of (2 S-MFMA -> pk-exp2 -> ONE
// ds_write_b128 into a private slot, permuted-key layout); then V b128
// loads (fill the LDS drain); Phase B = 8 chains of (ds_read_b128 ->
// 2 PV MFMA + 1 ones-MFMA). One lgkm drain per chunk, not per chain.
// ---------------------------------------------------------------------------
__global__ __launch_bounds__(256, 4)
void attn_mfma_kernel(const f16* __restrict__ qn,
                      const f16* __restrict__ kn,
                      const f16* __restrict__ vt,
                      f16* __restrict__ xo) {
  __shared__ __align__(16) f16 pbuf[4][8][16 * 40];  // 40KB
  const int tid  = threadIdx.x;
  const int wave = tid >> 6, lane = tid & 63;
  const int quad = lane >> 4, l16 = lane & 15;
  const int xcd = blockIdx.x & 7;
  const int idx = blockIdx.x >> 3;
  const int bth = ((idx & 15) << 3) | xcd;
  const int qpart = idx >> 4;  // 0..7
  const int qbase = qpart * 128 + wave * 32;
  const size_t hb = (size_t)bth * (LSEQ * DHEAD);
  f16* pw = &pbuf[wave][0][0];
  const int poff = l16 * 40 + quad * 8;  // in-slot offset (b128-aligned: 80B*l16+16B*quad)

  f16x8 qf[2];
#pragma unroll
  for (int qt = 0; qt < 2; ++qt)
    qf[qt] = *(const f16x8*)(qn + hb +
                             (size_t)(qbase + qt * 16 + l16) * DHEAD + quad * 8);

  const f16x8 ones = {(f16)1.f, (f16)1.f, (f16)1.f, (f16)1.f,
                      (f16)1.f, (f16)1.f, (f16)1.f, (f16)1.f};

  f32x4 oacc[2][2], ol[2];
#pragma unroll
  for (int qt = 0; qt < 2; ++qt) {
    ol[qt] = (f32x4){0.f, 0.f, 0.f, 0.f};
#pragma unroll
    for (int h = 0; h < 2; ++h) oacc[qt][h] = (f32x4){0.f, 0.f, 0.f, 0.f};
  }

  for (int kb = 0; kb < LSEQ; kb += 128) {
    // K A-frags: A[m=key][k=d] = K[kb+t*16+l16][quad*8+j]
    f16x8 kf[8];
#pragma unroll
    for (int t = 0; t < 8; ++t)
      kf[t] = *(const f16x8*)(kn + hb +
                              (size_t)(kb + t * 16 + l16) * DHEAD + quad * 8);

    // ---- Phase A: all 8 chains' S, exp, single-b128 P writes ----
#pragma unroll
    for (int c = 0; c < 4; ++c) {
#pragma unroll
      for (int qt = 0; qt < 2; ++qt) {
        const f32x4 z = {0.f, 0.f, 0.f, 0.f};
        // S^T tiles: D[row=key=quad*4+r][col=q=l16]
        f32x4 s0 = __builtin_amdgcn_mfma_f32_16x16x32_f16(kf[2 * c + 0],
                                                          qf[qt], z, 0, 0, 0);
        f32x4 s1 = __builtin_amdgcn_mfma_f32_16x16x32_f16(kf[2 * c + 1],
                                                          qf[qt], z, 0, 0, 0);
        union { f16x8 v; f16x2 h[4]; } p;
        p.h[0] = exp2pk(pkcvt(s0[0], s0[1]));   // key' quad*8+0..1
        p.h[1] = exp2pk(pkcvt(s0[2], s0[3]));   // key' quad*8+2..3
        p.h[2] = exp2pk(pkcvt(s1[0], s1[1]));   // key' quad*8+4..5
        p.h[3] = exp2pk(pkcvt(s1[2], s1[3]));   // key' quad*8+6..7
        *(f16x8*)(pw + (c * 2 + qt) * (16 * 40) + poff) = p.v;
      }
    }

    // ---- V B-frags (permuted layout -> contiguous b128); fills LDS drain ----
    f16x8 vv[4][2];
#pragma unroll
    for (int c = 0; c < 4; ++c)
#pragma unroll
      for (int h = 0; h < 2; ++h)
        vv[c][h] = *(const f16x8*)(vt + hb + (size_t)(h * 16 + l16) * LSEQ +
                                   kb + c * 32 + quad * 8);

    // ---- Phase B: all 8 chains' P read-back + PV/lsum MFMAs ----
#pragma unroll
    for (int c = 0; c < 4; ++c) {
#pragma unroll
      for (int qt = 0; qt < 2; ++qt) {
        f16x8 pf = *(const f16x8*)(pw + (c * 2 + qt) * (16 * 40) + poff);
        oacc[qt][0] = __builtin_amdgcn_mfma_f32_16x16x32_f16(pf, vv[c][0],
                                                             oacc[qt][0], 0, 0, 0);
        oacc[qt][1] = __builtin_amdgcn_mfma_f32_16x16x32_f16(pf, vv[c][1],
                                                             oacc[qt][1], 0, 0, 0);
        ol[qt] = __builtin_amdgcn_mfma_f32_16x16x32_f16(pf, ones, ol[qt],
                                                        0, 0, 0);
      }
    }
  }

  // epilogue: lane (quad,l16) holds rows quad*4+r; ol has lsum[row] in-lane
#pragma unroll
  for (int qt = 0; qt < 2; ++qt) {
#pragma unroll
    for (int r = 0; r < 4; ++r) {
      float inv = 1.f / ol[qt][r];
      int row = qbase + qt * 16 + quad * 4 + r;
#pragma unroll
      for (int h = 0; h < 2; ++h)
        xo[hb + (size_t)row * DHEAD + h * 16 + l16] =
            (f16)(oacc[qt][h][r] * inv);
    }
  }
}

// ---------------------------------------------------------------------------
// Kernel 3: out = xatt @ Wm^T + bm + residual, f32 out, via MFMA.
// Round-6 form (32 tok/block, grid 512) — the r7 16-tok split cost ~11 us.
// ---------------------------------------------------------------------------
__global__ __launch_bounds__(256, 4)
void out_proj_mfma_kernel(const f16* __restrict__ xatt,
                          const float* __restrict__ Wm,
                          const float* __restrict__ bm,
                          const float* __restrict__ resid,
                          float* __restrict__ out) {
  const int tid = threadIdx.x;
  const int wave = tid >> 6, lane = tid & 63;
  const int quad = lane >> 4, l16 = lane & 15;
  const int tokbase = blockIdx.x * 32;
  const int wbase = wave * 64;
  const int bt = tokbase >> 10, l0 = tokbase & 1023;

  f32x4 acc[2][4];  // [m=tok tile][n=och tile]
#pragma unroll
  for (int mt = 0; mt < 2; ++mt)
#pragma unroll
    for (int nt = 0; nt < 4; ++nt) acc[mt][nt] = (f32x4){0.f, 0.f, 0.f, 0.f};

#pragma unroll
  for (int kk = 0; kk < 8; ++kk) {
    const size_t hb = (size_t)(bt * HEADS + kk) * (LSEQ * DHEAD);
    f16x8 af[2], bf[4];
#pragma unroll
    for (int mt = 0; mt < 2; ++mt)
      af[mt] = *(const f16x8*)(xatt + hb +
                               (size_t)(l0 + mt * 16 + l16) * DHEAD + quad * 8);
#pragma unroll
    for (int nt = 0; nt < 4; ++nt)
      bf[nt] = cvt8(Wm + (size_t)(wbase + nt * 16 + l16) * CDIM + kk * 32 +
                    quad * 8);
#pragma unroll
    for (int mt = 0; mt < 2; ++mt)
#pragma unroll
      for (int nt = 0; nt < 4; ++nt)
        acc[mt][nt] = __builtin_amdgcn_mfma_f32_16x16x32_f16(af[mt], bf[nt],
                                                             acc[mt][nt], 0, 0, 0);
  }

#pragma unroll
  for (int nt = 0; nt < 4; ++nt) {
    const int och = wbase + nt * 16 + l16;
    const float bv = bm[och];
#pragma unroll
    for (int mt = 0; mt < 2; ++mt) {
#pragma unroll
      for (int r = 0; r < 4; ++r) {
        const int tok = tokbase + mt * 16 + quad * 4 + r;
        const size_t off = (size_t)tok * CDIM + och;
        out[off] = acc[mt][nt][r] + bv + resid[off];
      }
    }
  }
}

extern "C" void kernel_launch(void* const* d_in, const int* in_sizes, int n_in,
                              void* d_out, int out_size, void* d_ws,
                              size_t ws_size, hipStream_t stream) {
  const float* q  = (const float*)d_in[0];
  const float* k  = (const float*)d_in[1];
  const float* v  = (const float*)d_in[2];
  const float* Wq = (const float*)d_in[3];
  const float* bq = (const float*)d_in[4];
  const float* Wk = (const float*)d_in[5];
  const float* bk = (const float*)d_in[6];
  const float* Wv = (const float*)d_in[7];
  const float* bv = (const float*)d_in[8];
  const float* Wm = (const float*)d_in[9];
  const float* bm = (const float*)d_in[10];
  float* outp = (float*)d_out;

  f16* ws = (f16*)d_ws;
  const size_t TENS = (size_t)NTOK * CDIM;  // 4194304
  f16* qn  = ws;
  f16* kn  = ws + TENS;
  f16* vt  = ws + 2 * TENS;
  f16* xa  = ws + 3 * TENS;
  f16* w16 = xa;  // alias: consumed by proj_mfma before attn writes xa

  dim3 blk(256);
  cvt_w_kernel<<<dim3(192), blk, 0, stream>>>(Wq, Wk, Wv, w16);
  proj_mfma_kernel<<<dim3(512, 3), blk, 0, stream>>>(q, k, v, w16, bq, bk, bv,
                                                     qn, kn, vt);
  attn_mfma_kernel<<<dim3(1024), blk, 0, stream>>>(qn, kn, vt, xa);
  out_proj_mfma_kernel<<<dim3(512), blk, 0, stream>>>(xa, Wm, bm, q, outp);
}